// Round 2
// baseline (2898.636 us; speedup 1.0000x reference)
//
#include <hip/hip_runtime.h>

#define N_GRAPHS_C 256

__device__ __forceinline__ int xcc_id() {
    int x;
    asm volatile("s_getreg_b32 %0, hwreg(HW_REG_XCC_ID, 0, 4)" : "=s"(x));
    return x & 7;
}

// Per-edge math in (Angstrom, e, eV) units (avoids fp32 denormals from the
// reference's SI-unit charges). Accumulation layout: acc[rep][atom][4] =
// {fx, fy, fz, e}. FAST path: rep = physical XCD id, workgroup-scope atomics
// stay resident in that XCD's L2 (replica is 3.2 MB < 4 MB L2) instead of
// write-through RMW at the memory-side coherence point (which cost 32 B HBM
// write per atomic in round 1 -> 1.79 GB write stream).
template <bool FAST>
__global__ __launch_bounds__(256) void edge_kernel(
    const float* __restrict__ dij, const float* __restrict__ q,
    const float* __restrict__ g_ewald,
    const int* __restrict__ row, const int* __restrict__ col,
    float* __restrict__ acc, int n_atoms, int n_edges)
{
    int e = blockIdx.x * blockDim.x + threadIdx.x;
    if (e >= n_edges) return;

    float* my = acc;
    if (FAST) my += (size_t)xcc_id() * (size_t)n_atoms * 4;

    const float gA = g_ewald[0] * 1e-10f;   // 1/m -> 1/Angstrom
    const float KEV = (float)(8987551792.3 * 1.602176634e-9); // 14.3996 eV*A/e^2

    float dx = dij[3 * e + 0];
    float dy = dij[3 * e + 1];
    float dz = dij[3 * e + 2];
    int r = row[e];
    int c = col[e];
    float qr = q[r];
    float qc = q[c];

    float r2 = dx * dx + dy * dy + dz * dz;
    float inv_r = rsqrtf(r2);
    float rA = r2 * inv_r;                  // |dij| in Angstrom

    float pref = KEV * qr * qc * inv_r;     // eV

    float damp = 1.0f;
    if (rA < 2.2f)
        damp = __expf(-18.7f * (2.2f - rA) * (1.0f / 2.2f));

    float grij = gA * rA;
    float expm2 = __expf(-grij * grij);
    float t = 1.0f / (1.0f + 0.3275911f * grij);
    float erfc = t * (0.254829592f +
                 t * (-0.284496736f +
                 t * (1.421413741f +
                 t * (-1.453152027f +
                 t * 1.061405429f)))) * expm2;

    float ecoul = pref * (0.5f * damp + (erfc - 1.0f));          // eV
    float S = damp + erfc + 2.0f * grij * expm2 - 1.0f;
    float fs = pref * S * (inv_r * inv_r);                       // eV/A^2
    float fx = dx * fs, fy = dy * fs, fz = dz * fs;              // eV/A

    if (FAST) {
        // Workgroup-scope: atomic RMW executes in the local XCD L2 and the
        // line stays cached (no memory-side write-through). Correct because
        // every block indexing this replica shares this L2.
        __hip_atomic_fetch_add(&my[4 * r + 0], fx,    __ATOMIC_RELAXED, __HIP_MEMORY_SCOPE_WORKGROUP);
        __hip_atomic_fetch_add(&my[4 * r + 1], fy,    __ATOMIC_RELAXED, __HIP_MEMORY_SCOPE_WORKGROUP);
        __hip_atomic_fetch_add(&my[4 * r + 2], fz,    __ATOMIC_RELAXED, __HIP_MEMORY_SCOPE_WORKGROUP);
        __hip_atomic_fetch_add(&my[4 * r + 3], ecoul, __ATOMIC_RELAXED, __HIP_MEMORY_SCOPE_WORKGROUP);
        __hip_atomic_fetch_add(&my[4 * c + 0], -fx,   __ATOMIC_RELAXED, __HIP_MEMORY_SCOPE_WORKGROUP);
        __hip_atomic_fetch_add(&my[4 * c + 1], -fy,   __ATOMIC_RELAXED, __HIP_MEMORY_SCOPE_WORKGROUP);
        __hip_atomic_fetch_add(&my[4 * c + 2], -fz,   __ATOMIC_RELAXED, __HIP_MEMORY_SCOPE_WORKGROUP);
    } else {
        atomicAdd(&my[4 * r + 0], fx);
        atomicAdd(&my[4 * r + 1], fy);
        atomicAdd(&my[4 * r + 2], fz);
        atomicAdd(&my[4 * r + 3], ecoul);
        atomicAdd(&my[4 * c + 0], -fx);
        atomicAdd(&my[4 * c + 1], -fy);
        atomicAdd(&my[4 * c + 2], -fz);
    }
}

// Sum replicas -> force out + per-atom energy; then segmented (sorted batch)
// reduction to per-graph energy: wave-uniform check, shuffle reduce, one
// atomic per wave.
__global__ __launch_bounds__(256) void reduce_kernel(
    const float* __restrict__ acc, const int* __restrict__ batch,
    float* __restrict__ energy, float* __restrict__ force,
    int n_atoms, int n_rep)
{
    int i = blockIdx.x * blockDim.x + threadIdx.x;
    float fx = 0.f, fy = 0.f, fz = 0.f, en = 0.f;
    if (i < n_atoms) {
        const float4* a4 = (const float4*)acc;
        for (int k = 0; k < n_rep; ++k) {
            float4 v = a4[(size_t)k * n_atoms + i];
            fx += v.x; fy += v.y; fz += v.z; en += v.w;
        }
        force[3 * i + 0] = fx;
        force[3 * i + 1] = fy;
        force[3 * i + 2] = fz;
    }

    int ic = i < n_atoms ? i : (n_atoms - 1);
    int b = batch[ic];
    float v = (i < n_atoms) ? en : 0.0f;

    int b0 = __shfl(b, 0, 64);
    unsigned long long m = __ballot(b == b0);
    if (m == ~0ull) {
        for (int off = 32; off > 0; off >>= 1)
            v += __shfl_down(v, off, 64);
        if ((threadIdx.x & 63) == 0)
            atomicAdd(&energy[b0], v);
    } else {
        atomicAdd(&energy[b], v);
    }
}

extern "C" void kernel_launch(void* const* d_in, const int* in_sizes, int n_in,
                              void* d_out, int out_size, void* d_ws, size_t ws_size,
                              hipStream_t stream) {
    const float* dij      = (const float*)d_in[0];
    const float* q        = (const float*)d_in[1];
    const float* g_ewald  = (const float*)d_in[2];
    const int*   row      = (const int*)d_in[3];
    const int*   col      = (const int*)d_in[4];
    const int*   batch    = (const int*)d_in[5];

    int n_edges = in_sizes[0] / 3;
    int n_atoms = in_sizes[1];

    float* energy = (float*)d_out;               // [256]
    float* force  = (float*)d_out + N_GRAPHS_C;  // [n_atoms*3]
    float* acc    = (float*)d_ws;                // [n_rep][n_atoms][4]

    size_t need = (size_t)8 * n_atoms * 4 * sizeof(float);
    bool fast = ws_size >= need;
    int n_rep = fast ? 8 : 1;

    // d_out / d_ws are poisoned with 0xAA before every call.
    hipMemsetAsync(d_out, 0, (size_t)out_size * sizeof(float), stream);
    hipMemsetAsync(d_ws, 0, (size_t)n_rep * n_atoms * 4 * sizeof(float), stream);

    int threads = 256;
    int eblocks = (n_edges + threads - 1) / threads;
    if (fast)
        edge_kernel<true><<<eblocks, threads, 0, stream>>>(
            dij, q, g_ewald, row, col, acc, n_atoms, n_edges);
    else
        edge_kernel<false><<<eblocks, threads, 0, stream>>>(
            dij, q, g_ewald, row, col, acc, n_atoms, n_edges);

    int ablocks = (n_atoms + threads - 1) / threads;
    reduce_kernel<<<ablocks, threads, 0, stream>>>(
        acc, batch, energy, force, n_atoms, n_rep);
}

// Round 3
// 768.188 us; speedup vs baseline: 3.7733x; 3.7733x over previous
//
#include <hip/hip_runtime.h>

#define N_GRAPHS_C 256
#define CHUNK_LOG 13
#define CHUNK (1 << CHUNK_LOG)   // 8192 atoms per chunk -> 128 KB LDS
#define NSLICE 10                // edge slices per chunk
#define TPB 1024                 // 16 waves/CU (1 block/CU, LDS-bound)

// ---------------- shared per-edge math ----------------
// Units: Angstrom, electron charge, eV (avoids fp32 denormals from the
// reference's SI-unit charges; algebraically identical).
__device__ __forceinline__ void edge_math(
    float dx, float dy, float dz, float qr, float qc, float gA,
    float& fx, float& fy, float& fz, float& ecoul)
{
    const float KEV = (float)(8987551792.3 * 1.602176634e-9); // 14.3996 eV*A/e^2
    float r2 = dx * dx + dy * dy + dz * dz;
    float inv_r = rsqrtf(r2);
    float rA = r2 * inv_r;

    float pref = KEV * qr * qc * inv_r;

    float damp = 1.0f;
    if (rA < 2.2f)
        damp = __expf(-18.7f * (2.2f - rA) * (1.0f / 2.2f));

    float grij = gA * rA;
    float expm2 = __expf(-grij * grij);
    float t = 1.0f / (1.0f + 0.3275911f * grij);
    float erfc = t * (0.254829592f +
                 t * (-0.284496736f +
                 t * (1.421413741f +
                 t * (-1.453152027f +
                 t * 1.061405429f)))) * expm2;

    ecoul = pref * (0.5f * damp + (erfc - 1.0f));
    float S = damp + erfc + 2.0f * grij * expm2 - 1.0f;
    float fs = pref * S * (inv_r * inv_r);
    fx = dx * fs; fy = dy * fs; fz = dz * fs;
}

// ---------------- main path: chunked LDS privatization ----------------
// Block (c, p): atoms [c*CHUNK, (c+1)*CHUNK) privately in LDS, edge slice p.
// No global atomics: LDS ds_add_f32 accumulate, then plain coalesced spill of
// the float4 partial to ws[(c*NSLICE+p)*CHUNK ...].
__global__ __launch_bounds__(TPB) void chunk_kernel(
    const float* __restrict__ dij, const float* __restrict__ q,
    const float* __restrict__ g_ewald,
    const int* __restrict__ row, const int* __restrict__ col,
    float* __restrict__ partial,
    int n_edges, int n_chunks, int n_slices)
{
    __shared__ float acc[CHUNK * 4];

    int c = blockIdx.x % n_chunks;
    int p = blockIdx.x / n_chunks;
    int cbase = c << CHUNK_LOG;

    for (int i = threadIdx.x; i < CHUNK * 4; i += TPB) acc[i] = 0.f;
    __syncthreads();

    const float gA = g_ewald[0] * 1e-10f;   // 1/m -> 1/Angstrom

    // slice bounds in int4 (4-edge) groups
    int n4 = (n_edges + 3) >> 2;
    int g0 = (int)((long long)p * n4 / n_slices);
    int g1 = (int)((long long)(p + 1) * n4 / n_slices);

    const int4* row4 = (const int4*)row;
    const int4* col4 = (const int4*)col;

    for (int g = g0 + threadIdx.x; g < g1; g += TPB) {
        int4 r4 = row4[g];
        int4 c4 = col4[g];
        int rr[4] = {r4.x, r4.y, r4.z, r4.w};
        int cc[4] = {c4.x, c4.y, c4.z, c4.w};
        #pragma unroll
        for (int j = 0; j < 4; ++j) {
            int e = 4 * g + j;
            if (e >= n_edges) break;
            int rl = rr[j] - cbase;
            int cl = cc[j] - cbase;
            bool hr = (unsigned)rl < (unsigned)CHUNK;
            bool hc = (unsigned)cl < (unsigned)CHUNK;
            if (!(hr || hc)) continue;

            float dx = dij[3 * e + 0];
            float dy = dij[3 * e + 1];
            float dz = dij[3 * e + 2];
            float qr = q[rr[j]];
            float qc = q[cc[j]];
            float fx, fy, fz, ec;
            edge_math(dx, dy, dz, qr, qc, gA, fx, fy, fz, ec);

            if (hr) {
                atomicAdd(&acc[4 * rl + 0], fx);
                atomicAdd(&acc[4 * rl + 1], fy);
                atomicAdd(&acc[4 * rl + 2], fz);
                atomicAdd(&acc[4 * rl + 3], ec);
            }
            if (hc) {
                atomicAdd(&acc[4 * cl + 0], -fx);
                atomicAdd(&acc[4 * cl + 1], -fy);
                atomicAdd(&acc[4 * cl + 2], -fz);
            }
        }
    }
    __syncthreads();

    // spill partial: coalesced float4 stores, fully deterministic (no memset needed)
    float4* dst = (float4*)partial + (size_t)(c * n_slices + p) * CHUNK;
    const float4* src = (const float4*)acc;
    for (int i = threadIdx.x; i < CHUNK; i += TPB) dst[i] = src[i];
}

// Sum the NSLICE partials per atom -> force + per-atom energy; segmented
// (sorted batch) per-graph energy reduction: one atomic per wave-run.
__global__ __launch_bounds__(256) void finalize_kernel(
    const float* __restrict__ partial, const int* __restrict__ batch,
    float* __restrict__ energy, float* __restrict__ force,
    int n_atoms, int n_slices)
{
    int i = blockIdx.x * blockDim.x + threadIdx.x;
    float fx = 0.f, fy = 0.f, fz = 0.f, en = 0.f;
    if (i < n_atoms) {
        int c = i >> CHUNK_LOG;
        int l = i & (CHUNK - 1);
        const float4* base = (const float4*)partial + (size_t)c * n_slices * CHUNK + l;
        for (int p = 0; p < n_slices; ++p) {
            float4 v = base[(size_t)p * CHUNK];
            fx += v.x; fy += v.y; fz += v.z; en += v.w;
        }
        force[3 * i + 0] = fx;
        force[3 * i + 1] = fy;
        force[3 * i + 2] = fz;
    }

    int ic = i < n_atoms ? i : (n_atoms - 1);
    int b = batch[ic];
    float v = (i < n_atoms) ? en : 0.0f;
    int b0 = __shfl(b, 0, 64);
    unsigned long long m = __ballot(b == b0);
    if (m == ~0ull) {
        for (int off = 32; off > 0; off >>= 1)
            v += __shfl_down(v, off, 64);
        if ((threadIdx.x & 63) == 0)
            atomicAdd(&energy[b0], v);
    } else {
        atomicAdd(&energy[b], v);
    }
}

// ---------------- fallback path (ws too small): round-1 atomics ----------------
__global__ __launch_bounds__(256) void edge_kernel_atomic(
    const float* __restrict__ dij, const float* __restrict__ q,
    const float* __restrict__ g_ewald,
    const int* __restrict__ row, const int* __restrict__ col,
    float* __restrict__ e_atom, float* __restrict__ force, int n_edges)
{
    int e = blockIdx.x * blockDim.x + threadIdx.x;
    if (e >= n_edges) return;
    const float gA = g_ewald[0] * 1e-10f;
    float dx = dij[3 * e], dy = dij[3 * e + 1], dz = dij[3 * e + 2];
    int r = row[e], c = col[e];
    float fx, fy, fz, ec;
    edge_math(dx, dy, dz, q[r], q[c], gA, fx, fy, fz, ec);
    atomicAdd(&e_atom[r], ec);
    atomicAdd(&force[3 * r + 0], fx);
    atomicAdd(&force[3 * r + 1], fy);
    atomicAdd(&force[3 * r + 2], fz);
    atomicAdd(&force[3 * c + 0], -fx);
    atomicAdd(&force[3 * c + 1], -fy);
    atomicAdd(&force[3 * c + 2], -fz);
}

__global__ __launch_bounds__(256) void atom_kernel_atomic(
    const float* __restrict__ e_atom, const int* __restrict__ batch,
    float* __restrict__ energy, int n_atoms)
{
    int i = blockIdx.x * blockDim.x + threadIdx.x;
    int ic = i < n_atoms ? i : (n_atoms - 1);
    float v = (i < n_atoms) ? e_atom[ic] : 0.0f;
    int b = batch[ic];
    int b0 = __shfl(b, 0, 64);
    unsigned long long m = __ballot(b == b0);
    if (m == ~0ull) {
        for (int off = 32; off > 0; off >>= 1)
            v += __shfl_down(v, off, 64);
        if ((threadIdx.x & 63) == 0)
            atomicAdd(&energy[b0], v);
    } else {
        atomicAdd(&energy[b], v);
    }
}

extern "C" void kernel_launch(void* const* d_in, const int* in_sizes, int n_in,
                              void* d_out, int out_size, void* d_ws, size_t ws_size,
                              hipStream_t stream) {
    const float* dij     = (const float*)d_in[0];
    const float* q       = (const float*)d_in[1];
    const float* g_ewald = (const float*)d_in[2];
    const int*   row     = (const int*)d_in[3];
    const int*   col     = (const int*)d_in[4];
    const int*   batch   = (const int*)d_in[5];

    int n_edges = in_sizes[0] / 3;
    int n_atoms = in_sizes[1];

    float* energy = (float*)d_out;               // [256]
    float* force  = (float*)d_out + N_GRAPHS_C;  // [n_atoms*3]

    int n_chunks = (n_atoms + CHUNK - 1) >> CHUNK_LOG;
    size_t need = (size_t)n_chunks * NSLICE * CHUNK * 4 * sizeof(float);

    if (ws_size >= need) {
        // energy[] is atomically accumulated -> zero it (harness poisons 0xAA).
        hipMemsetAsync(d_out, 0, N_GRAPHS_C * sizeof(float), stream);
        chunk_kernel<<<n_chunks * NSLICE, TPB, 0, stream>>>(
            dij, q, g_ewald, row, col, (float*)d_ws, n_edges, n_chunks, NSLICE);
        int ablocks = (n_atoms + 255) / 256;
        finalize_kernel<<<ablocks, 256, 0, stream>>>(
            (const float*)d_ws, batch, energy, force, n_atoms, NSLICE);
    } else {
        // fallback: global-atomic scatter (round-1 behavior)
        float* e_atom = (float*)d_ws;            // [n_atoms]
        hipMemsetAsync(d_out, 0, (size_t)out_size * sizeof(float), stream);
        hipMemsetAsync(d_ws, 0, (size_t)n_atoms * sizeof(float), stream);
        int eblocks = (n_edges + 255) / 256;
        edge_kernel_atomic<<<eblocks, 256, 0, stream>>>(
            dij, q, g_ewald, row, col, e_atom, force, n_edges);
        int ablocks = (n_atoms + 255) / 256;
        atom_kernel_atomic<<<ablocks, 256, 0, stream>>>(
            e_atom, batch, energy, n_atoms);
    }
}

// Round 4
// 626.307 us; speedup vs baseline: 4.6281x; 1.2265x over previous
//
#include <hip/hip_runtime.h>

#define N_GRAPHS_C 256
#define CHUNK_LOG 13
#define CHUNK (1 << CHUNK_LOG)   // 8192 atoms per bucket
#define MAXB 32                  // max buckets the fast path supports
#define NSLICE 10                // record slices per bucket in pass B
#define TILE_G 4096              // int4 groups per passA block = 16384 edges
#define TPA 256
#define TPBB 1024

// ---------------- shared per-edge math ----------------
// Units: Angstrom, electron charge, eV (avoids fp32 denormals from the
// reference's SI-unit charges; algebraically identical).
__device__ __forceinline__ void edge_math(
    float dx, float dy, float dz, float qr, float qc, float gA,
    float& fx, float& fy, float& fz, float& ecoul)
{
    const float KEV = (float)(8987551792.3 * 1.602176634e-9); // 14.3996 eV*A/e^2
    float r2 = dx * dx + dy * dy + dz * dz;
    float inv_r = rsqrtf(r2);
    float rA = r2 * inv_r;

    float pref = KEV * qr * qc * inv_r;

    float damp = 1.0f;
    if (rA < 2.2f)
        damp = __expf(-18.7f * (2.2f - rA) * (1.0f / 2.2f));

    float grij = gA * rA;
    float expm2 = __expf(-grij * grij);
    float t = 1.0f / (1.0f + 0.3275911f * grij);
    float erfc = t * (0.254829592f +
                 t * (-0.284496736f +
                 t * (1.421413741f +
                 t * (-1.453152027f +
                 t * 1.061405429f)))) * expm2;

    ecoul = pref * (0.5f * damp + (erfc - 1.0f));
    float S = damp + erfc + 2.0f * grij * expm2 - 1.0f;
    float fs = pref * S * (inv_r * inv_r);
    fx = dx * fs; fy = dy * fs; fz = dz * fs;
}

// ================= fast path: dense compute + binned scatter =================

// Pass A: one dense pass over edges. Per block tile of 16K edges:
//   1) LDS histogram of bucket ids (row>>13, col>>13)
//   2) one global cursor atomicAdd per bucket per block (tiny)
//   3) main pass: math once per edge (all lanes active), emit two float4
//      records (+f for row, -f for col, .w = local atom idx) at base+rank,
//      and accumulate energy directly per-graph (batch[row]) in LDS.
__global__ __launch_bounds__(TPA) void passA(
    const float* __restrict__ dij, const float* __restrict__ q,
    const float* __restrict__ g_ewald,
    const int* __restrict__ row, const int* __restrict__ col,
    const int* __restrict__ batch,
    unsigned* __restrict__ cursor, float4* __restrict__ records, int cap,
    float* __restrict__ e_part, int nblkA,
    int n_edges, int nb)
{
    __shared__ unsigned cnt[MAXB];
    __shared__ unsigned base[MAXB];
    __shared__ float e_graph[N_GRAPHS_C];

    int tid = threadIdx.x;
    if (tid < MAXB) cnt[tid] = 0u;
    for (int i = tid; i < N_GRAPHS_C; i += TPA) e_graph[i] = 0.f;
    __syncthreads();

    int n4 = n_edges >> 2;                   // n_edges % 4 == 0 on fast path
    int g0 = blockIdx.x * TILE_G;
    int g1 = min(g0 + TILE_G, n4);

    const int4* row4 = (const int4*)row;
    const int4* col4 = (const int4*)col;
    const float4* dij4 = (const float4*)dij;

    // ---- count pass ----
    for (int g = g0 + tid; g < g1; g += TPA) {
        int4 r4 = row4[g];
        int4 c4 = col4[g];
        atomicAdd(&cnt[r4.x >> CHUNK_LOG], 1u);
        atomicAdd(&cnt[r4.y >> CHUNK_LOG], 1u);
        atomicAdd(&cnt[r4.z >> CHUNK_LOG], 1u);
        atomicAdd(&cnt[r4.w >> CHUNK_LOG], 1u);
        atomicAdd(&cnt[c4.x >> CHUNK_LOG], 1u);
        atomicAdd(&cnt[c4.y >> CHUNK_LOG], 1u);
        atomicAdd(&cnt[c4.z >> CHUNK_LOG], 1u);
        atomicAdd(&cnt[c4.w >> CHUNK_LOG], 1u);
    }
    __syncthreads();
    if (tid < nb) base[tid] = atomicAdd(&cursor[tid], cnt[tid]);
    __syncthreads();
    if (tid < MAXB) cnt[tid] = 0u;
    __syncthreads();

    const float gA = g_ewald[0] * 1e-10f;    // 1/m -> 1/Angstrom

    // ---- main pass ----
    for (int g = g0 + tid; g < g1; g += TPA) {
        int4 r4 = row4[g];
        int4 c4 = col4[g];
        float4 d0 = dij4[3 * g + 0];
        float4 d1 = dij4[3 * g + 1];
        float4 d2 = dij4[3 * g + 2];
        float ex[4] = {d0.x, d0.w, d1.z, d2.y};
        float ey[4] = {d0.y, d1.x, d1.w, d2.z};
        float ez[4] = {d0.z, d1.y, d2.x, d2.w};
        int rr[4] = {r4.x, r4.y, r4.z, r4.w};
        int cc[4] = {c4.x, c4.y, c4.z, c4.w};
        #pragma unroll
        for (int j = 0; j < 4; ++j) {
            int r = rr[j], c = cc[j];
            float fx, fy, fz, ec;
            edge_math(ex[j], ey[j], ez[j], q[r], q[c], gA, fx, fy, fz, ec);

            atomicAdd(&e_graph[batch[r]], ec);

            int br = r >> CHUNK_LOG, bc = c >> CHUNK_LOG;
            unsigned pr = base[br] + atomicAdd(&cnt[br], 1u);
            unsigned pc = base[bc] + atomicAdd(&cnt[bc], 1u);
            if (pr < (unsigned)cap)
                records[(size_t)br * cap + pr] =
                    make_float4(fx, fy, fz, __uint_as_float((unsigned)(r & (CHUNK - 1))));
            if (pc < (unsigned)cap)
                records[(size_t)bc * cap + pc] =
                    make_float4(-fx, -fy, -fz, __uint_as_float((unsigned)(c & (CHUNK - 1))));
        }
    }
    __syncthreads();

    // deterministic per-block energy partials (no global atomics)
    for (int g2 = tid; g2 < N_GRAPHS_C; g2 += TPA)
        e_part[(size_t)g2 * nblkA + blockIdx.x] = e_graph[g2];
}

// Pass B: block (b,s) streams its slice of bucket b's records (coalesced
// float4) and accumulates into a 96 KB LDS force array with full lane
// activation; spills deterministic partials.
__global__ __launch_bounds__(TPBB) void passB(
    const float4* __restrict__ records, const unsigned* __restrict__ cursor,
    int cap, float* __restrict__ partial, int nslice)
{
    __shared__ float acc[3 * CHUNK];
    int b = blockIdx.x / nslice;
    int s = blockIdx.x % nslice;

    for (int i = threadIdx.x; i < 3 * CHUNK; i += TPBB) acc[i] = 0.f;
    __syncthreads();

    unsigned n = min(cursor[b], (unsigned)cap);
    unsigned r0 = (unsigned)((unsigned long long)s * n / nslice);
    unsigned r1 = (unsigned)((unsigned long long)(s + 1) * n / nslice);
    const float4* rec = records + (size_t)b * cap;

    for (unsigned i = r0 + threadIdx.x; i < r1; i += TPBB) {
        float4 v = rec[i];
        unsigned idx = __float_as_uint(v.w) & (CHUNK - 1);
        atomicAdd(&acc[idx], v.x);
        atomicAdd(&acc[CHUNK + idx], v.y);
        atomicAdd(&acc[2 * CHUNK + idx], v.z);
    }
    __syncthreads();

    float* dst = partial + (size_t)blockIdx.x * 3 * CHUNK;
    for (int i = threadIdx.x; i < 3 * CHUNK; i += TPBB) dst[i] = acc[i];
}

__global__ __launch_bounds__(256) void fin_force(
    const float* __restrict__ partial, float* __restrict__ force,
    int n_atoms, int nslice)
{
    int a = blockIdx.x * 256 + threadIdx.x;
    if (a >= n_atoms) return;
    int b = a >> CHUNK_LOG, l = a & (CHUNK - 1);
    const float* p = partial + (size_t)b * nslice * 3 * CHUNK + l;
    float fx = 0.f, fy = 0.f, fz = 0.f;
    for (int s = 0; s < nslice; ++s) {
        const float* ps = p + (size_t)s * 3 * CHUNK;
        fx += ps[0]; fy += ps[CHUNK]; fz += ps[2 * CHUNK];
    }
    force[3 * a + 0] = fx;
    force[3 * a + 1] = fy;
    force[3 * a + 2] = fz;
}

__global__ __launch_bounds__(64) void fin_energy(
    const float* __restrict__ e_part, float* __restrict__ energy, int nblkA)
{
    int g = blockIdx.x;
    const float* p = e_part + (size_t)g * nblkA;
    float s = 0.f;
    for (int i = threadIdx.x; i < nblkA; i += 64) s += p[i];
    for (int off = 32; off > 0; off >>= 1) s += __shfl_down(s, off, 64);
    if (threadIdx.x == 0) energy[g] = s;
}

// ================= fallback 1: round-3 chunk-scan path =================
__global__ __launch_bounds__(1024) void chunk_kernel(
    const float* __restrict__ dij, const float* __restrict__ q,
    const float* __restrict__ g_ewald,
    const int* __restrict__ row, const int* __restrict__ col,
    float* __restrict__ partial, int n_edges, int n_chunks, int n_slices)
{
    __shared__ float acc[CHUNK * 4];
    int c = blockIdx.x % n_chunks;
    int p = blockIdx.x / n_chunks;
    int cbase = c << CHUNK_LOG;
    for (int i = threadIdx.x; i < CHUNK * 4; i += 1024) acc[i] = 0.f;
    __syncthreads();
    const float gA = g_ewald[0] * 1e-10f;
    int n4 = (n_edges + 3) >> 2;
    int g0 = (int)((long long)p * n4 / n_slices);
    int g1 = (int)((long long)(p + 1) * n4 / n_slices);
    const int4* row4 = (const int4*)row;
    const int4* col4 = (const int4*)col;
    for (int g = g0 + threadIdx.x; g < g1; g += 1024) {
        int4 r4 = row4[g];
        int4 c4 = col4[g];
        int rr[4] = {r4.x, r4.y, r4.z, r4.w};
        int cc[4] = {c4.x, c4.y, c4.z, c4.w};
        #pragma unroll
        for (int j = 0; j < 4; ++j) {
            int e = 4 * g + j;
            if (e >= n_edges) break;
            int rl = rr[j] - cbase;
            int cl = cc[j] - cbase;
            bool hr = (unsigned)rl < (unsigned)CHUNK;
            bool hc = (unsigned)cl < (unsigned)CHUNK;
            if (!(hr || hc)) continue;
            float fx, fy, fz, ec;
            edge_math(dij[3 * e], dij[3 * e + 1], dij[3 * e + 2],
                      q[rr[j]], q[cc[j]], gA, fx, fy, fz, ec);
            if (hr) {
                atomicAdd(&acc[4 * rl + 0], fx);
                atomicAdd(&acc[4 * rl + 1], fy);
                atomicAdd(&acc[4 * rl + 2], fz);
                atomicAdd(&acc[4 * rl + 3], ec);
            }
            if (hc) {
                atomicAdd(&acc[4 * cl + 0], -fx);
                atomicAdd(&acc[4 * cl + 1], -fy);
                atomicAdd(&acc[4 * cl + 2], -fz);
            }
        }
    }
    __syncthreads();
    float4* dst = (float4*)partial + (size_t)(c * n_slices + p) * CHUNK;
    const float4* src = (const float4*)acc;
    for (int i = threadIdx.x; i < CHUNK; i += 1024) dst[i] = src[i];
}

__global__ __launch_bounds__(256) void finalize_kernel(
    const float* __restrict__ partial, const int* __restrict__ batch,
    float* __restrict__ energy, float* __restrict__ force,
    int n_atoms, int n_slices)
{
    int i = blockIdx.x * blockDim.x + threadIdx.x;
    float fx = 0.f, fy = 0.f, fz = 0.f, en = 0.f;
    if (i < n_atoms) {
        int c = i >> CHUNK_LOG;
        int l = i & (CHUNK - 1);
        const float4* base = (const float4*)partial + (size_t)c * n_slices * CHUNK + l;
        for (int p = 0; p < n_slices; ++p) {
            float4 v = base[(size_t)p * CHUNK];
            fx += v.x; fy += v.y; fz += v.z; en += v.w;
        }
        force[3 * i + 0] = fx;
        force[3 * i + 1] = fy;
        force[3 * i + 2] = fz;
    }
    int ic = i < n_atoms ? i : (n_atoms - 1);
    int b = batch[ic];
    float v = (i < n_atoms) ? en : 0.0f;
    int b0 = __shfl(b, 0, 64);
    unsigned long long m = __ballot(b == b0);
    if (m == ~0ull) {
        for (int off = 32; off > 0; off >>= 1)
            v += __shfl_down(v, off, 64);
        if ((threadIdx.x & 63) == 0) atomicAdd(&energy[b0], v);
    } else {
        atomicAdd(&energy[b], v);
    }
}

// ================= fallback 2: pure global atomics =================
__global__ __launch_bounds__(256) void edge_kernel_atomic(
    const float* __restrict__ dij, const float* __restrict__ q,
    const float* __restrict__ g_ewald,
    const int* __restrict__ row, const int* __restrict__ col,
    float* __restrict__ e_atom, float* __restrict__ force, int n_edges)
{
    int e = blockIdx.x * blockDim.x + threadIdx.x;
    if (e >= n_edges) return;
    const float gA = g_ewald[0] * 1e-10f;
    int r = row[e], c = col[e];
    float fx, fy, fz, ec;
    edge_math(dij[3 * e], dij[3 * e + 1], dij[3 * e + 2], q[r], q[c], gA,
              fx, fy, fz, ec);
    atomicAdd(&e_atom[r], ec);
    atomicAdd(&force[3 * r + 0], fx);
    atomicAdd(&force[3 * r + 1], fy);
    atomicAdd(&force[3 * r + 2], fz);
    atomicAdd(&force[3 * c + 0], -fx);
    atomicAdd(&force[3 * c + 1], -fy);
    atomicAdd(&force[3 * c + 2], -fz);
}

__global__ __launch_bounds__(256) void atom_kernel_atomic(
    const float* __restrict__ e_atom, const int* __restrict__ batch,
    float* __restrict__ energy, int n_atoms)
{
    int i = blockIdx.x * blockDim.x + threadIdx.x;
    int ic = i < n_atoms ? i : (n_atoms - 1);
    float v = (i < n_atoms) ? e_atom[ic] : 0.0f;
    int b = batch[ic];
    int b0 = __shfl(b, 0, 64);
    unsigned long long m = __ballot(b == b0);
    if (m == ~0ull) {
        for (int off = 32; off > 0; off >>= 1)
            v += __shfl_down(v, off, 64);
        if ((threadIdx.x & 63) == 0) atomicAdd(&energy[b0], v);
    } else {
        atomicAdd(&energy[b], v);
    }
}

extern "C" void kernel_launch(void* const* d_in, const int* in_sizes, int n_in,
                              void* d_out, int out_size, void* d_ws, size_t ws_size,
                              hipStream_t stream) {
    const float* dij     = (const float*)d_in[0];
    const float* q       = (const float*)d_in[1];
    const float* g_ewald = (const float*)d_in[2];
    const int*   row     = (const int*)d_in[3];
    const int*   col     = (const int*)d_in[4];
    const int*   batch   = (const int*)d_in[5];

    int n_edges = in_sizes[0] / 3;
    int n_atoms = in_sizes[1];

    float* energy = (float*)d_out;               // [256]
    float* force  = (float*)d_out + N_GRAPHS_C;  // [n_atoms*3]

    int nb = (n_atoms + CHUNK - 1) >> CHUNK_LOG;
    int n4 = n_edges >> 2;
    int nblkA = (n4 + TILE_G - 1) / TILE_G;

    // capacity per bucket: expected 2E/nb + ~3.5% margin, 1024-rounded
    long long expect = (long long)2 * n_edges / (nb > 0 ? nb : 1);
    int cap = (int)(((expect + expect / 32 + 4096) + 1023) / 1024 * 1024);

    // ws layout (256B-aligned regions)
    size_t off_cursor  = 0;
    size_t off_records = 256;
    size_t sz_records  = (size_t)nb * cap * sizeof(float4);
    size_t off_partial = (off_records + sz_records + 255) & ~(size_t)255;
    size_t sz_partial  = (size_t)nb * NSLICE * 3 * CHUNK * sizeof(float);
    size_t off_epart   = (off_partial + sz_partial + 255) & ~(size_t)255;
    size_t sz_epart    = (size_t)N_GRAPHS_C * nblkA * sizeof(float);
    size_t need_fast   = off_epart + sz_epart;

    bool fast = (nb <= MAXB) && ((n_edges & 3) == 0) && (ws_size >= need_fast);

    if (fast) {
        char* ws = (char*)d_ws;
        unsigned* cursor = (unsigned*)(ws + off_cursor);
        float4* records  = (float4*)(ws + off_records);
        float* partial   = (float*)(ws + off_partial);
        float* e_part    = (float*)(ws + off_epart);

        hipMemsetAsync(cursor, 0, MAXB * sizeof(unsigned), stream);

        passA<<<nblkA, TPA, 0, stream>>>(
            dij, q, g_ewald, row, col, batch,
            cursor, records, cap, e_part, nblkA, n_edges, nb);

        passB<<<nb * NSLICE, TPBB, 0, stream>>>(
            records, cursor, cap, partial, NSLICE);

        fin_force<<<(n_atoms + 255) / 256, 256, 0, stream>>>(
            partial, force, n_atoms, NSLICE);

        fin_energy<<<N_GRAPHS_C, 64, 0, stream>>>(e_part, energy, nblkA);
    } else {
        size_t need_chunk = (size_t)nb * NSLICE * CHUNK * 4 * sizeof(float);
        if (ws_size >= need_chunk) {
            hipMemsetAsync(d_out, 0, N_GRAPHS_C * sizeof(float), stream);
            chunk_kernel<<<nb * NSLICE, 1024, 0, stream>>>(
                dij, q, g_ewald, row, col, (float*)d_ws, n_edges, nb, NSLICE);
            finalize_kernel<<<(n_atoms + 255) / 256, 256, 0, stream>>>(
                (const float*)d_ws, batch, energy, force, n_atoms, NSLICE);
        } else {
            float* e_atom = (float*)d_ws;
            hipMemsetAsync(d_out, 0, (size_t)out_size * sizeof(float), stream);
            hipMemsetAsync(d_ws, 0, (size_t)n_atoms * sizeof(float), stream);
            edge_kernel_atomic<<<(n_edges + 255) / 256, 256, 0, stream>>>(
                dij, q, g_ewald, row, col, e_atom, force, n_edges);
            atom_kernel_atomic<<<(n_atoms + 255) / 256, 256, 0, stream>>>(
                e_atom, batch, energy, n_atoms);
        }
    }
}